// Round 1
// baseline (432.609 us; speedup 1.0000x reference)
//
#include <hip/hip_runtime.h>

#define KWORDS 16

// Exact replication of the reference decision:
//   guess index arithmetically (within +/-1 of true nearest), then refine with
//   the same float32 comparisons the reference performs against the REAL
//   codebook values: step down if |v-c[i-1]| <= |v-c[i]| (tie -> lower),
//   step up only if |v-c[i+1]| < best (tie stays lower).
__device__ __forceinline__ float quant_one(float v, const float* __restrict__ c,
                                           float c0, float inv_step) {
    float f = (v - c0) * inv_step;
    int i = (int)floorf(f + 0.5f);
    i = i < 0 ? 0 : (i > KWORDS - 1 ? KWORDS - 1 : i);
    int im = i > 0 ? i - 1 : 0;
    int ip = i < KWORDS - 1 ? i + 1 : KWORDS - 1;
    float ci = c[i];
    float cm = c[im];
    float cp = c[ip];
    float di = fabsf(v - ci);
    float dm = fabsf(v - cm);
    float dp = fabsf(v - cp);
    float r = ci;
    float dbest = di;
    if (dm <= dbest) { r = cm; dbest = dm; }   // tie-break toward lower codeword
    if (dp < dbest)  { r = cp; }               // strictly closer only
    return r;
}

__global__ __launch_bounds__(256) void QuantizerUniformLayer_78975858639646_kernel(
    const float4* __restrict__ x, const float* __restrict__ cb,
    float4* __restrict__ out, int nvec,
    const float* __restrict__ x_tail, float* __restrict__ out_tail, int rem)
{
    __shared__ float c[KWORDS];
    if (threadIdx.x < KWORDS) c[threadIdx.x] = cb[threadIdx.x];
    __syncthreads();

    const float c0 = c[0];
    const float inv_step = (float)(KWORDS - 1) / (c[KWORDS - 1] - c[0]);

    const int stride = gridDim.x * blockDim.x;
    for (int idx = blockIdx.x * blockDim.x + threadIdx.x; idx < nvec; idx += stride) {
        float4 v = x[idx];
        float4 r;
        r.x = quant_one(v.x, c, c0, inv_step);
        r.y = quant_one(v.y, c, c0, inv_step);
        r.z = quant_one(v.z, c, c0, inv_step);
        r.w = quant_one(v.w, c, c0, inv_step);
        out[idx] = r;
    }

    // scalar tail (n % 4 != 0) — not hit for 8192x8192 but keep it correct
    if (blockIdx.x == 0 && (int)threadIdx.x < rem) {
        float v = x_tail[threadIdx.x];
        out_tail[threadIdx.x] = quant_one(v, c, c0, inv_step);
    }
}

extern "C" void kernel_launch(void* const* d_in, const int* in_sizes, int n_in,
                              void* d_out, int out_size, void* d_ws, size_t ws_size,
                              hipStream_t stream) {
    const float* x  = (const float*)d_in[0];
    const float* cb = (const float*)d_in[1];
    float* out = (float*)d_out;

    const int n    = in_sizes[0];
    const int nvec = n / 4;
    const int rem  = n - nvec * 4;

    const int block = 256;
    const int grid  = 8192;  // 2M threads, 8 float4 each at n=64M; grid-stride handles any n

    QuantizerUniformLayer_78975858639646_kernel<<<grid, block, 0, stream>>>(
        (const float4*)x, cb, (float4*)out, nvec,
        x + (size_t)nvec * 4, out + (size_t)nvec * 4, rem);
}

// Round 3
// 414.193 us; speedup vs baseline: 1.0445x; 1.0445x over previous
//
#include <hip/hip_runtime.h>

#define KWORDS 16
#define BLOCK  256
#define VPT    8   // float4 vectors per thread

// clang-native 16B vector so __builtin_nontemporal_* accepts it
typedef float vfloat4 __attribute__((ext_vector_type(4)));

// Exact replication of the reference decision:
//   guess index arithmetically (within +/-1 of true nearest), then refine with
//   the same float32 comparisons the reference performs against the REAL
//   codebook values loaded from memory: step down if |v-c[i-1]| <= |v-c[i]|
//   (tie -> lower), step up only if |v-c[i+1]| < best (tie stays lower).
//   Output is always an exact loaded codebook value -> absmax 0.
__device__ __forceinline__ float quant_one(float v, const float* __restrict__ c,
                                           float c0, float inv_step) {
    float f = (v - c0) * inv_step;
    int i = (int)floorf(f + 0.5f);
    i = i < 0 ? 0 : (i > KWORDS - 1 ? KWORDS - 1 : i);
    int im = i > 0 ? i - 1 : 0;
    int ip = i < KWORDS - 1 ? i + 1 : KWORDS - 1;
    float ci = c[i];
    float cm = c[im];
    float cp = c[ip];
    float di = fabsf(v - ci);
    float dm = fabsf(v - cm);
    float dp = fabsf(v - cp);
    float r = ci;
    float dbest = di;
    if (dm <= dbest) { r = cm; dbest = dm; }   // tie-break toward lower codeword
    if (dp < dbest)  { r = cp; }               // strictly closer only
    return r;
}

__device__ __forceinline__ vfloat4 quant_vec(vfloat4 v, const float* __restrict__ c,
                                             float c0, float inv_step) {
    vfloat4 r;
    r.x = quant_one(v.x, c, c0, inv_step);
    r.y = quant_one(v.y, c, c0, inv_step);
    r.z = quant_one(v.z, c, c0, inv_step);
    r.w = quant_one(v.w, c, c0, inv_step);
    return r;
}

__global__ __launch_bounds__(BLOCK) void QuantizerUniformLayer_78975858639646_kernel(
    const vfloat4* __restrict__ x, const float* __restrict__ cb,
    vfloat4* __restrict__ out, int nvec,
    const float* __restrict__ x_tail, float* __restrict__ out_tail, int rem)
{
    __shared__ float c[KWORDS];
    if (threadIdx.x < KWORDS) c[threadIdx.x] = cb[threadIdx.x];
    __syncthreads();

    const float c0 = c[0];
    const float inv_step = (float)(KWORDS - 1) / (c[KWORDS - 1] - c0);

    const int base = blockIdx.x * (BLOCK * VPT) + threadIdx.x;

    if (base + (VPT - 1) * BLOCK < nvec) {
        // full tile: issue all 8 nontemporal loads up front, then compute+store
        vfloat4 v[VPT];
#pragma unroll
        for (int j = 0; j < VPT; ++j)
            v[j] = __builtin_nontemporal_load(&x[base + j * BLOCK]);
#pragma unroll
        for (int j = 0; j < VPT; ++j) {
            vfloat4 r = quant_vec(v[j], c, c0, inv_step);
            __builtin_nontemporal_store(r, &out[base + j * BLOCK]);
        }
    } else {
        // ragged last tile
#pragma unroll
        for (int j = 0; j < VPT; ++j) {
            int idx = base + j * BLOCK;
            if (idx < nvec) {
                vfloat4 v = __builtin_nontemporal_load(&x[idx]);
                vfloat4 r = quant_vec(v, c, c0, inv_step);
                __builtin_nontemporal_store(r, &out[idx]);
            }
        }
    }

    // scalar tail (n % 4 != 0) — not hit for 8192x8192 but keep it correct
    if (blockIdx.x == 0 && (int)threadIdx.x < rem) {
        float v = x_tail[threadIdx.x];
        out_tail[threadIdx.x] = quant_one(v, c, c0, inv_step);
    }
}

extern "C" void kernel_launch(void* const* d_in, const int* in_sizes, int n_in,
                              void* d_out, int out_size, void* d_ws, size_t ws_size,
                              hipStream_t stream) {
    const float* x  = (const float*)d_in[0];
    const float* cb = (const float*)d_in[1];
    float* out = (float*)d_out;

    const int n    = in_sizes[0];
    const int nvec = n / 4;
    const int rem  = n - nvec * 4;

    const int grid = (nvec + BLOCK * VPT - 1) / (BLOCK * VPT);  // 8192 at n=64M

    QuantizerUniformLayer_78975858639646_kernel<<<(grid > 0 ? grid : 1), BLOCK, 0, stream>>>(
        (const vfloat4*)x, cb, (vfloat4*)out, nvec,
        x + (size_t)nvec * 4, out + (size_t)nvec * 4, rem);
}